// Round 10
// baseline (223.560 us; speedup 1.0000x reference)
//
#include <hip/hip_runtime.h>
#include <math.h>

#define BB 256
#define SSEQ 128
#define INPUT 256
#define PD 128
#define EE 64
#define RW 256
#define MM 512
#define WW 64
#define KD 384          // IN_DIM

typedef _Float16 half8 __attribute__((ext_vector_type(8)));
typedef __fp16 fp16x2 __attribute__((ext_vector_type(2)));
typedef float float4v __attribute__((ext_vector_type(4)));
typedef float f32x16 __attribute__((ext_vector_type(16)));
typedef unsigned int uint2v __attribute__((ext_vector_type(2)));

#define LOG2E 1.44269504088896f
#define OUT1 8388608u

// LDS byte layout (R3 map).
// Phase A (prologue): [0,128K) = Wq x-part f16 image, chunk kb*256+n = k 8kb..8kb+7 @ col n.
// Phase B (flash):    [0,64K)  = mem f16 rows (chunk m*8 + (c^(m&7))),
//                     [64K,128K) = memT f16 (chunk w*64 + (cm^(w&7))).
// [128K, 128K+6K) f32 scratch.
#define MEMT16   4096            // memT base in uint4 units (64K/16)
#define F32_OFF  131072
#define LDS_BYTES (131072 + 6144)
#define UE_O 0
#define PE_O 64
#define QPE_O 192
#define QP_O 448                  // qpart [1024]

union H8 { half8 h8; unsigned int u[4]; uint4 u4; };

__device__ __forceinline__ unsigned int pk2(float a, float b) {
    union { fp16x2 h; unsigned int u; } p;
    p.h = __builtin_amdgcn_cvt_pkrtz(a, b);
    return p.u;
}

// v_permlane32_swap_b32 via the builtin (NOT inline asm: two "+v" asm operands
// holding the same value can be coalesced into ONE physical VGPR -> self-swap
// garbage; R1's absmax=4.6e7 failure.)
// returns r[0] = [a_lo | b_lo], r[1] = [a_hi | b_hi]
__device__ __forceinline__ float xhalf_max(float v) {
    uint2v r = __builtin_amdgcn_permlane32_swap(__float_as_uint(v), __float_as_uint(v), false, false);
    return fmaxf(__uint_as_float(r[0]), __uint_as_float(r[1]));
}
__device__ __forceinline__ float xhalf_sum(float v) {
    uint2v r = __builtin_amdgcn_permlane32_swap(__float_as_uint(v), __float_as_uint(v), false, false);
    return __uint_as_float(r[0]) + __uint_as_float(r[1]);
}

// ---------------- flash loop, instantiated twice (clean / store-augmented) ----
// STORE_FS=false: byte-identical to R7's loop (best measured: 73.9us/dispatch).
// STORE_FS=true : block 255 only -- unconditional pv stores + Ml log replace
//                 the old QK-recompute tail (straggler kill, R9 idea done right).
template<bool STORE_FS>
__device__ __forceinline__ void flash_loop(
    const uint4* __restrict__ sm128, const H8* bqf,
    f32x16& Oa0, f32x16& Oa1, float& Ml, float& llp,
    const int l31, const int hh, const int mswz, const int mt0,
    float* __restrict__ fsBase, float* __restrict__ mlBase)
{
    H8 afc[4];
    #pragma unroll
    for (int kc = 0; kc < 4; ++kc)
        afc[kc].u4 = sm128[(mt0*32 + l31)*8 + (((kc<<1) + hh) ^ mswz)];

    for (int i = 0; i < 16; ++i) {
        const int mtile = (i + mt0) & 15;
        f32x16 Sa = (f32x16)0.f;
        __builtin_amdgcn_s_setprio(1);
        #pragma unroll
        for (int kc = 0; kc < 4; ++kc)
            Sa = __builtin_amdgcn_mfma_f32_32x32x16_f16(afc[kc].h8, bqf[kc].h8, Sa, 0, 0, 0);
        __builtin_amdgcn_s_setprio(0);
        if (i < 15) {
            const int mrow = ((i + 1 + mt0) & 15)*32 + l31;
            #pragma unroll
            for (int kc = 0; kc < 4; ++kc)
                afc[kc].u4 = sm128[mrow*8 + (((kc<<1) + hh) ^ mswz)];
        }
        const int c0 = mtile*4 + hh;
        H8 afP0, afP1, afP2, afP3;
        afP0.u4 = sm128[MEMT16 + l31*64        + ( c0      ^ mswz)];
        afP1.u4 = sm128[MEMT16 + l31*64        + ((c0 + 2) ^ mswz)];
        afP2.u4 = sm128[MEMT16 + (32 + l31)*64 + ( c0      ^ mswz)];
        afP3.u4 = sm128[MEMT16 + (32 + l31)*64 + ((c0 + 2) ^ mswz)];
        float m0 = fmaxf(fmaxf(Sa[0], Sa[1]), Sa[2]);
        float m1 = fmaxf(fmaxf(Sa[3], Sa[4]), Sa[5]);
        float m2 = fmaxf(fmaxf(Sa[6], Sa[7]), Sa[8]);
        float m3 = fmaxf(fmaxf(Sa[9], Sa[10]), Sa[11]);
        float m4 = fmaxf(fmaxf(Sa[12], Sa[13]), Sa[14]);
        float m5 = fmaxf(fmaxf(m0, m1), Sa[15]);
        float m6 = fmaxf(fmaxf(m2, m3), m4);
        float tmx = xhalf_max(fmaxf(m5, m6));
        // defer-max (T13): rescale only when running max grows by > 8 (log2).
        if (__any(tmx > Ml + 8.0f)) {
            float Mn = fmaxf(Ml, tmx);
            float al = __builtin_amdgcn_exp2f(Ml - Mn);
            Ml = Mn;
            llp *= al;
            #pragma unroll
            for (int g = 0; g < 16; ++g) { Oa0[g] *= al; Oa1[g] *= al; }
        }
        float pv[16];
        #pragma unroll
        for (int g = 0; g < 16; ++g) pv[g] = __builtin_amdgcn_exp2f(Sa[g] - Ml);
        float ts = (((pv[0]+pv[1])+(pv[2]+pv[3])) + ((pv[4]+pv[5])+(pv[6]+pv[7])))
                 + (((pv[8]+pv[9])+(pv[10]+pv[11])) + ((pv[12]+pv[13])+(pv[14]+pv[15])));
        llp += ts;
        if constexpr (STORE_FS) {
            // unnormalized pv -> final_state region; scale fixed after the loop
            float* fp = fsBase + mtile*32 + hh*4;
            *(float4*)(fp +  0) = make_float4(pv[0],  pv[1],  pv[2],  pv[3]);
            *(float4*)(fp +  8) = make_float4(pv[4],  pv[5],  pv[6],  pv[7]);
            *(float4*)(fp + 16) = make_float4(pv[8],  pv[9],  pv[10], pv[11]);
            *(float4*)(fp + 24) = make_float4(pv[12], pv[13], pv[14], pv[15]);
            mlBase[mtile*64] = Ml;
        }
        uint2v rA0 = __builtin_amdgcn_permlane32_swap(pk2(pv[0],pv[1]),   pk2(pv[4],pv[5]),   false, false);
        uint2v rB0 = __builtin_amdgcn_permlane32_swap(pk2(pv[2],pv[3]),   pk2(pv[6],pv[7]),   false, false);
        uint2v rA1 = __builtin_amdgcn_permlane32_swap(pk2(pv[8],pv[9]),   pk2(pv[12],pv[13]), false, false);
        uint2v rB1 = __builtin_amdgcn_permlane32_swap(pk2(pv[10],pv[11]), pk2(pv[14],pv[15]), false, false);
        H8 bp0; bp0.u[0]=rA0[0]; bp0.u[1]=rB0[0]; bp0.u[2]=rA0[1]; bp0.u[3]=rB0[1];
        H8 bp1; bp1.u[0]=rA1[0]; bp1.u[1]=rB1[0]; bp1.u[2]=rA1[1]; bp1.u[3]=rB1[1];
        __builtin_amdgcn_s_setprio(1);
        Oa0 = __builtin_amdgcn_mfma_f32_32x32x16_f16(afP0.h8, bp0.h8, Oa0, 0, 0, 0);
        Oa0 = __builtin_amdgcn_mfma_f32_32x32x16_f16(afP1.h8, bp1.h8, Oa0, 0, 0, 0);
        Oa1 = __builtin_amdgcn_mfma_f32_32x32x16_f16(afP2.h8, bp0.h8, Oa1, 0, 0, 0);
        Oa1 = __builtin_amdgcn_mfma_f32_32x32x16_f16(afP3.h8, bp1.h8, Oa1, 0, 0, 0);
        __builtin_amdgcn_s_setprio(0);
    }
}

// ---------- single fused kernel: 256 blocks x 1024 threads (16 waves) ----------
// HARD-WON CONSTRAINTS (do not violate):
//  * launch_bounds (1024,4): 4 waves/SIMD -> 128 unified regs/wave. Flash loop
//    uses EXACTLY that. ANY extra live state in the flash loop spills (R5).
//    32 waves/CU would need <=64 regs: impossible. LDS shrink can't help.
//  * NO barriers inside phase Q or the flash loop (R6: +8.5us).
//  * NO conditional global-store path inside the SHARED flash loop (R9:
//    if(dofix) store in the common loop -> uniform 1.8x slowdown across ALL
//    blocks, MfmaUtil 11->6.3. Specialize the loop per-block instead).
//  * Flash body: 32x32x16 swapped-operand, permlane-only cross-lane, defer-max
//    THR=8, QK-frag prefetch, setprio, per-sq rotation+sleep desync (R7, -3%).
// R10: straggler kill via template<STORE_FS> loop split. Blocks 0..254 run the
//  R7 loop verbatim; block 255 runs the store-augmented copy, then a cheap
//  global fixup (scale = exp2(mlog - Ml_final)*inv) replaces the old serial
//  QK-recompute tail. Prologue-A keeps b128 conflict-free staging writes.
__global__ void __launch_bounds__(1024, 4)
attn_kernel(const float* __restrict__ x, const int* __restrict__ user_id,
            const float* __restrict__ uet, const float* __restrict__ W_proc,
            const float* __restrict__ b_proc, const float* __restrict__ Wq,
            const float* __restrict__ memG, float* __restrict__ out,
            float* __restrict__ wsf)
{
    extern __shared__ char smraw[];
    unsigned short* smemu = (unsigned short*)smraw;
    uint4*          sm128 = (uint4*)smraw;
    float*          smf   = (float*)(smraw + F32_OFF);

    const int t = threadIdx.x;
    const int b = blockIdx.x;
    const int lane = t & 63, wv = t >> 6;        // 16 waves
    const int n16 = lane & 15, quad = lane >> 4;
    const int l31 = lane & 31, hh = lane >> 5;
    const int r = wv & 3, sq = wv >> 2;          // sq 0..3
    const int s0 = sq * 32;
    const int mswz = l31 & 7;

    const int uid = user_id[b];
    const int sid = uid & 15;
    const float* memB = memG + (size_t)sid * (MM*WW);
    const float* wqX  = Wq + (size_t)sid * KD * RW;

    if (t < EE) smf[UE_O + t] = uet[(size_t)uid*EE + t];

    // ---- Prologue A: Wq x-part -> LDS f16 image, b128 conflict-free writes ----
    {
        const int n = t & 255, h = t >> 8;       // n fixed per thread, h 0..3
        for (int i = 0; i < 8; ++i) {
            const int kb = i*4 + h;              // chunk row group: k = 8kb..8kb+7
            const float* wr = wqX + (size_t)(8*kb)*RW + n;
            float w[8];
            #pragma unroll
            for (int j = 0; j < 8; ++j) w[j] = wr[(size_t)j*RW];
            sm128[kb*256 + n] =
                make_uint4(pk2(w[0],w[1]), pk2(w[2],w[3]), pk2(w[4],w[5]), pk2(w[6],w[7]));
        }
    }
    __syncthreads();

    // pe
    if (t < PD) {
        float a = b_proc[t];
        #pragma unroll
        for (int e = 0; e < EE; ++e) a = fmaf(smf[UE_O + e], W_proc[e*PD + t], a);
        smf[PE_O + t] = a;
    }
    __syncthreads();
    // qpe partials: 4 independent chains so the 32 loads can hoist
    {
        int n = t & 255, h = t >> 8;
        const float* wr = wqX + (size_t)(256 + h*32)*RW + n;
        float sa = 0.f, sb = 0.f, sc = 0.f, sd = 0.f;
        #pragma unroll
        for (int k = 0; k < 32; k += 4) {
            sa = fmaf(smf[PE_O + h*32 + k],     wr[(size_t)(k)*RW],     sa);
            sb = fmaf(smf[PE_O + h*32 + k + 1], wr[(size_t)(k + 1)*RW], sb);
            sc = fmaf(smf[PE_O + h*32 + k + 2], wr[(size_t)(k + 2)*RW], sc);
            sd = fmaf(smf[PE_O + h*32 + k + 3], wr[(size_t)(k + 3)*RW], sd);
        }
        smf[QP_O + h*256 + n] = (sa + sb) + (sc + sd);
    }
    __syncthreads();
    if (t < 256) smf[QPE_O + t] = LOG2E * (smf[QP_O + t] + smf[QP_O + 256 + t]
                                         + smf[QP_O + 512 + t] + smf[QP_O + 768 + t]);
    __syncthreads();

    // ---- Phase Q (x-part k<256 only; pe via qpe bias; kc MUST stop at 8) ----
    float4v qacc[4][2];
    #pragma unroll
    for (int mt = 0; mt < 4; ++mt)
        #pragma unroll
        for (int nt = 0; nt < 2; ++nt) qacc[mt][nt] = (float4v)0.f;

    const float* xB = x + (size_t)(b*SSEQ + s0) * INPUT;
    for (int kc = 0; kc < 8; ++kc) {
        H8 afr[4];
        #pragma unroll
        for (int mt = 0; mt < 4; ++mt)
            afr[mt].u4 = sm128[(kc*4 + quad)*256 + r*64 + mt*16 + n16];
        H8 bfr[2];
        #pragma unroll
        for (int nt = 0; nt < 2; ++nt) {
            const float* xg = xB + (size_t)(nt*16 + n16)*INPUT + kc*32 + quad*8;
            float4 a0 = *(const float4*)xg;
            float4 a1 = *(const float4*)(xg + 4);
            bfr[nt].u[0] = pk2(a0.x*LOG2E, a0.y*LOG2E);
            bfr[nt].u[1] = pk2(a0.z*LOG2E, a0.w*LOG2E);
            bfr[nt].u[2] = pk2(a1.x*LOG2E, a1.y*LOG2E);
            bfr[nt].u[3] = pk2(a1.z*LOG2E, a1.w*LOG2E);
        }
        __builtin_amdgcn_s_setprio(1);
        #pragma unroll
        for (int mt = 0; mt < 4; ++mt)
            #pragma unroll
            for (int nt = 0; nt < 2; ++nt)
                qacc[mt][nt] = __builtin_amdgcn_mfma_f32_16x16x32_f16(afr[mt].h8, bfr[nt].h8, qacc[mt][nt], 0, 0, 0);
        __builtin_amdgcn_s_setprio(0);
    }
    #pragma unroll
    for (int mt = 0; mt < 4; ++mt)
        #pragma unroll
        for (int reg = 0; reg < 4; ++reg) {
            float qv = smf[QPE_O + r*64 + mt*16 + quad*4 + reg];
            #pragma unroll
            for (int nt = 0; nt < 2; ++nt) qacc[mt][nt][reg] += qv;
        }
    unsigned int pkq[4][2][2];
    #pragma unroll
    for (int mt = 0; mt < 4; ++mt)
        #pragma unroll
        for (int nt = 0; nt < 2; ++nt) {
            pkq[mt][nt][0] = pk2(qacc[mt][nt][0], qacc[mt][nt][1]);
            pkq[mt][nt][1] = pk2(qacc[mt][nt][2], qacc[mt][nt][3]);
        }
    // ---- repack q into 32x32x16 B-operand layout (one-time) ----
    H8 bqf[4];
    {
        const int ntSel = (lane >> 4) & 1;           // = bit4 of s5
        const int srcBase = (lane & 15) + (lane & 32);
        #pragma unroll
        for (int kc = 0; kc < 4; ++kc)
            #pragma unroll
            for (int jp = 0; jp < 4; ++jp) {
                const int src = srcBase + ((jp >> 1) << 4);
                int v0 = __shfl((int)pkq[kc][0][jp & 1], src, 64);
                int v1 = __shfl((int)pkq[kc][1][jp & 1], src, 64);
                bqf[kc].u[jp] = (unsigned int)(ntSel ? v1 : v0);
            }
    }
    __syncthreads();                             // all waves done reading Wq image

    // ---- Prologue B: overwrite LDS with mem f16 images (convert + transpose) ----
    for (int i = 0; i < 4; ++i) {
        int id = t + i*1024;
        int m = id >> 3, cw = id & 7;
        const float* g = memB + m*64 + cw*8;
        float4 a0 = *(const float4*)g;
        float4 a1 = *(const float4*)(g + 4);
        sm128[m*8 + (cw ^ (m & 7))] =
            make_uint4(pk2(a0.x,a0.y), pk2(a0.z,a0.w), pk2(a1.x,a1.y), pk2(a1.z,a1.w));
    }
    __syncthreads();
    for (int i = 0; i < 4; ++i) {
        int id = t + i*1024;
        int w = id & 63, cm = id >> 6;
        unsigned int uu[4];
        #pragma unroll
        for (int p = 0; p < 4; ++p) {
            int m0 = cm*8 + 2*p, m1 = m0 + 1;
            unsigned short lo = smemu[m0*64 + (((w>>3) ^ (m0&7))<<3) + (w&7)];
            unsigned short hi = smemu[m1*64 + (((w>>3) ^ (m1&7))<<3) + (w&7)];
            uu[p] = (unsigned int)lo | ((unsigned int)hi << 16);
        }
        sm128[MEMT16 + w*64 + (cm ^ (w & 7))] = make_uint4(uu[0],uu[1],uu[2],uu[3]);
    }
    __syncthreads();

    // ========== flash loop: rotated + staggered per sq; split by block ==========
    if (sq == 1) __builtin_amdgcn_s_sleep(2);
    else if (sq == 2) __builtin_amdgcn_s_sleep(4);
    else if (sq == 3) __builtin_amdgcn_s_sleep(6);

    f32x16 Oa0 = (f32x16)0.f, Oa1 = (f32x16)0.f;
    float Ml = -1e30f, llp = 0.f;
    const int mt0 = sq * 4;
    const bool dofix = (b == BB - 1) && (wsf != nullptr);
    const int s = s0 + l31;
    float* fsBase = out + (size_t)OUT1 + ((size_t)(s*4 + r) << 9);   // final_state row
    float* mlBase = wsf ? (wsf + (size_t)wv*16*64 + lane) : nullptr; // Ml log

    if (!dofix) {
        flash_loop<false>(sm128, bqf, Oa0, Oa1, Ml, llp, l31, hh, mswz, mt0,
                          fsBase, mlBase);
    } else {
        flash_loop<true>(sm128, bqf, Oa0, Oa1, Ml, llp, l31, hh, mswz, mt0,
                         fsBase, mlBase);
    }

    // combine the two half-partials of the denominator (lane <-> lane^32)
    float inv = 1.0f / xhalf_sum(llp);

    // ---- store read_words ----
    {
        float* op = out + ((size_t)(b*SSEQ + s)*4 + r)*WW;
        #pragma unroll
        for (int rq = 0; rq < 4; ++rq) {
            float4 o0 = make_float4(Oa0[rq*4+0]*inv, Oa0[rq*4+1]*inv,
                                    Oa0[rq*4+2]*inv, Oa0[rq*4+3]*inv);
            *(float4*)&op[rq*8 + hh*4] = o0;
            float4 o1 = make_float4(Oa1[rq*4+0]*inv, Oa1[rq*4+1]*inv,
                                    Oa1[rq*4+2]*inv, Oa1[rq*4+3]*inv);
            *(float4*)&op[32 + rq*8 + hh*4] = o1;
        }
    }

    // ---- final_state fixup (b == 255, workspace path): rescale stored pv ----
    if (dofix) {
        asm volatile("s_waitcnt vmcnt(0) lgkmcnt(0)" ::: "memory");   // drain pv/Ml stores
        for (int mtile = 0; mtile < 16; ++mtile) {
            float mlog = mlBase[mtile*64];
            float scale = __builtin_amdgcn_exp2f(mlog - Ml) * inv;
            float* fp = fsBase + mtile*32 + hh*4;
            #pragma unroll
            for (int rq = 0; rq < 4; ++rq) {
                float4 v = *(float4*)(fp + rq*8);
                v.x *= scale; v.y *= scale; v.z *= scale; v.w *= scale;
                *(float4*)(fp + rq*8) = v;
            }
        }
    } else if (b == BB - 1) {
        // fallback: old QK-recompute tail (no workspace available)
        size_t base = (size_t)OUT1 + ((size_t)(s*4 + r) << 9);
        for (int mtile = 0; mtile < 16; ++mtile) {
            f32x16 Sa = (f32x16)0.f;
            const int mrow = mtile*32 + l31;
            #pragma unroll
            for (int kc = 0; kc < 4; ++kc) {
                H8 af; af.u4 = sm128[mrow*8 + (((kc<<1) + hh) ^ mswz)];
                Sa = __builtin_amdgcn_mfma_f32_32x32x16_f16(af.h8, bqf[kc].h8, Sa, 0, 0, 0);
            }
            #pragma unroll
            for (int rq = 0; rq < 4; ++rq) {
                float4 w4 = make_float4(
                    __builtin_amdgcn_exp2f(Sa[rq*4+0] - Ml) * inv,
                    __builtin_amdgcn_exp2f(Sa[rq*4+1] - Ml) * inv,
                    __builtin_amdgcn_exp2f(Sa[rq*4+2] - Ml) * inv,
                    __builtin_amdgcn_exp2f(Sa[rq*4+3] - Ml) * inv);
                *(float4*)&out[base + mtile*32 + rq*8 + hh*4] = w4;
            }
        }
    }
}

extern "C" void kernel_launch(void* const* d_in, const int* in_sizes, int n_in,
                              void* d_out, int out_size, void* d_ws, size_t ws_size,
                              hipStream_t stream) {
    const float* x    = (const float*)d_in[0];
    const int*   uid  = (const int*)  d_in[1];
    const float* uet  = (const float*)d_in[2];
    const float* Wp   = (const float*)d_in[3];
    const float* bp   = (const float*)d_in[4];
    const float* Wq   = (const float*)d_in[5];
    const float* mem  = (const float*)d_in[6];
    float* out = (float*)d_out;
    float* wsf = (d_ws != nullptr && ws_size >= 65536) ? (float*)d_ws : nullptr;

    (void)hipFuncSetAttribute((const void*)attn_kernel,
                              hipFuncAttributeMaxDynamicSharedMemorySize, LDS_BYTES);
    attn_kernel<<<BB, 1024, LDS_BYTES, stream>>>(x, uid, uet, Wp, bp, Wq, mem, out, wsf);
}

// Round 11
// 162.742 us; speedup vs baseline: 1.3737x; 1.3737x over previous
//
#include <hip/hip_runtime.h>
#include <math.h>

#define BB 256
#define SSEQ 128
#define INPUT 256
#define PD 128
#define EE 64
#define RW 256
#define MM 512
#define WW 64
#define KD 384          // IN_DIM

typedef _Float16 half8 __attribute__((ext_vector_type(8)));
typedef __fp16 fp16x2 __attribute__((ext_vector_type(2)));
typedef float float4v __attribute__((ext_vector_type(4)));
typedef float f32x16 __attribute__((ext_vector_type(16)));
typedef unsigned int uint2v __attribute__((ext_vector_type(2)));

#define LOG2E 1.44269504088896f
#define OUT1 8388608u

// LDS byte layout (R3 map).
// Phase A (prologue): [0,128K) = Wq x-part f16 image, chunk c = (k>>3)*256 + n.
// Phase B (flash):    [0,64K)  = mem f16 rows (chunk m*8 + (c^(m&7))),
//                     [64K,128K) = memT f16 (chunk w*64 + (cm^(w&7))).
// [128K, 128K+6K) f32 scratch.
#define MEMT16   4096            // memT base in uint4 units (64K/16)
#define F32_OFF  131072
#define LDS_BYTES (131072 + 6144)
#define UE_O 0
#define PE_O 64
#define QPE_O 192
#define QP_O 448                  // qpart [1024]

union H8 { half8 h8; unsigned int u[4]; uint4 u4; };

__device__ __forceinline__ unsigned int pk2(float a, float b) {
    union { fp16x2 h; unsigned int u; } p;
    p.h = __builtin_amdgcn_cvt_pkrtz(a, b);
    return p.u;
}

// v_permlane32_swap_b32 via the builtin (NOT inline asm: two "+v" asm operands
// holding the same value can be coalesced into ONE physical VGPR -> self-swap
// garbage. That was R1's absmax=4.6e7 failure.)
// returns r[0] = [a_lo | b_lo], r[1] = [a_hi | b_hi]
__device__ __forceinline__ float xhalf_max(float v) {
    uint2v r = __builtin_amdgcn_permlane32_swap(__float_as_uint(v), __float_as_uint(v), false, false);
    return fmaxf(__uint_as_float(r[0]), __uint_as_float(r[1]));
}
__device__ __forceinline__ float xhalf_sum(float v) {
    uint2v r = __builtin_amdgcn_permlane32_swap(__float_as_uint(v), __float_as_uint(v), false, false);
    return __uint_as_float(r[0]) + __uint_as_float(r[1]);
}

// ---------- single fused kernel: 256 blocks x 1024 threads (16 waves) ----------
// HARD-WON CONSTRAINTS (do not violate):
//  * launch_bounds (1024,4): 4 waves/SIMD -> 128 unified regs/wave. The flash
//    loop uses EXACTLY that (64 arch + ~64 acc). ANY extra live state across
//    the flash loop spills or degrades codegen globally -- R5 (mtile pairing,
//    +26MB spill), R9/R10 (straggler-kill ws pointers + dual loop copies:
//    uniform 1.8x slowdown at unchanged VGPR_Count=64). Even a few extra live
//    pointer VGPRs tip it. (1024,8) needs <=64 regs: impossible.
//  * NO barriers inside phase Q or the flash loop (R6: +8.5us).
//  * NO conditional global-store path in the flash loop, and NO extra kernel
//    args / derived pointers live across it (R9/R10).
//  * No multi-pass restructure of the flash loop (old-R8: spills, 4x slower).
//  * Flash body: 32x32x16 swapped-operand, permlane-only cross-lane, defer-max
//    THR=8, QK-frag prefetch, setprio, per-sq rotation+sleep desync (R7, -3%).
// R11 = R7 verbatim (best verified: 73.9us/dispatch, bench 162.7us). The
// straggler-kill arc (R8-R10) is abandoned: tail is worth <=5us, both
// implementations cost ~60us via global codegen perturbation.
__global__ void __launch_bounds__(1024, 4)
attn_kernel(const float* __restrict__ x, const int* __restrict__ user_id,
            const float* __restrict__ uet, const float* __restrict__ W_proc,
            const float* __restrict__ b_proc, const float* __restrict__ Wq,
            const float* __restrict__ memG, float* __restrict__ out)
{
    extern __shared__ char smraw[];
    unsigned short* smemu = (unsigned short*)smraw;
    unsigned int*   smw   = (unsigned int*)smraw;
    uint4*          sm128 = (uint4*)smraw;
    float*          smf   = (float*)(smraw + F32_OFF);

    const int t = threadIdx.x;
    const int b = blockIdx.x;
    const int lane = t & 63, wv = t >> 6;        // 16 waves
    const int n16 = lane & 15, quad = lane >> 4;
    const int l31 = lane & 31, hh = lane >> 5;
    const int r = wv & 3, sq = wv >> 2;          // sq 0..3
    const int s0 = sq * 32;
    const int mswz = l31 & 7;

    const int uid = user_id[b];
    const int sid = uid & 15;
    const float* memB = memG + (size_t)sid * (MM*WW);
    const float* wqX  = Wq + (size_t)sid * KD * RW;

    if (t < EE) smf[UE_O + t] = uet[(size_t)uid*EE + t];

    // ---- Prologue A: Wq x-part -> LDS f16 image [k/8][n][k%8], unrolled x4 ----
    {
        const int n = t & 255, h = t >> 8;       // n fixed per thread
        for (int i = 0; i < 32; i += 4) {
            float w[8];
            #pragma unroll
            for (int j = 0; j < 4; ++j) {
                int kp = (i + j)*4 + h;
                w[2*j]   = wqX[(size_t)(2*kp)    *RW + n];
                w[2*j+1] = wqX[(size_t)(2*kp + 1)*RW + n];
            }
            #pragma unroll
            for (int j = 0; j < 4; ++j) {
                int kp = (i + j)*4 + h;
                smw[((((kp>>2)*256 + n) << 2) | (kp & 3))] = pk2(w[2*j], w[2*j+1]);
            }
        }
    }
    __syncthreads();

    // pe
    if (t < PD) {
        float a = b_proc[t];
        #pragma unroll
        for (int e = 0; e < EE; ++e) a = fmaf(smf[UE_O + e], W_proc[e*PD + t], a);
        smf[PE_O + t] = a;
    }
    __syncthreads();
    // qpe partials: 4 independent chains so the 32 loads can hoist
    {
        int n = t & 255, h = t >> 8;
        const float* wr = wqX + (size_t)(256 + h*32)*RW + n;
        float sa = 0.f, sb = 0.f, sc = 0.f, sd = 0.f;
        #pragma unroll
        for (int k = 0; k < 32; k += 4) {
            sa = fmaf(smf[PE_O + h*32 + k],     wr[(size_t)(k)*RW],     sa);
            sb = fmaf(smf[PE_O + h*32 + k + 1], wr[(size_t)(k + 1)*RW], sb);
            sc = fmaf(smf[PE_O + h*32 + k + 2], wr[(size_t)(k + 2)*RW], sc);
            sd = fmaf(smf[PE_O + h*32 + k + 3], wr[(size_t)(k + 3)*RW], sd);
        }
        smf[QP_O + h*256 + n] = (sa + sb) + (sc + sd);
    }
    __syncthreads();
    if (t < 256) smf[QPE_O + t] = LOG2E * (smf[QP_O + t] + smf[QP_O + 256 + t]
                                         + smf[QP_O + 512 + t] + smf[QP_O + 768 + t]);
    __syncthreads();

    // ---- Phase Q (x-part k<256 only; pe via qpe bias; kc MUST stop at 8) ----
    float4v qacc[4][2];
    #pragma unroll
    for (int mt = 0; mt < 4; ++mt)
        #pragma unroll
        for (int nt = 0; nt < 2; ++nt) qacc[mt][nt] = (float4v)0.f;

    const float* xB = x + (size_t)(b*SSEQ + s0) * INPUT;
    for (int kc = 0; kc < 8; ++kc) {
        H8 afr[4];
        #pragma unroll
        for (int mt = 0; mt < 4; ++mt)
            afr[mt].u4 = sm128[(kc*4 + quad)*256 + r*64 + mt*16 + n16];
        H8 bfr[2];
        #pragma unroll
        for (int nt = 0; nt < 2; ++nt) {
            const float* xg = xB + (size_t)(nt*16 + n16)*INPUT + kc*32 + quad*8;
            float4 a0 = *(const float4*)xg;
            float4 a1 = *(const float4*)(xg + 4);
            bfr[nt].u[0] = pk2(a0.x*LOG2E, a0.y*LOG2E);
            bfr[nt].u[1] = pk2(a0.z*LOG2E, a0.w*LOG2E);
            bfr[nt].u[2] = pk2(a1.x*LOG2E, a1.y*LOG2E);
            bfr[nt].u[3] = pk2(a1.z*LOG2E, a1.w*LOG2E);
        }
        __builtin_amdgcn_s_setprio(1);
        #pragma unroll
        for (int mt = 0; mt < 4; ++mt)
            #pragma unroll
            for (int nt = 0; nt < 2; ++nt)
                qacc[mt][nt] = __builtin_amdgcn_mfma_f32_16x16x32_f16(afr[mt].h8, bfr[nt].h8, qacc[mt][nt], 0, 0, 0);
        __builtin_amdgcn_s_setprio(0);
    }
    #pragma unroll
    for (int mt = 0; mt < 4; ++mt)
        #pragma unroll
        for (int reg = 0; reg < 4; ++reg) {
            float qv = smf[QPE_O + r*64 + mt*16 + quad*4 + reg];
            #pragma unroll
            for (int nt = 0; nt < 2; ++nt) qacc[mt][nt][reg] += qv;
        }
    unsigned int pkq[4][2][2];
    #pragma unroll
    for (int mt = 0; mt < 4; ++mt)
        #pragma unroll
        for (int nt = 0; nt < 2; ++nt) {
            pkq[mt][nt][0] = pk2(qacc[mt][nt][0], qacc[mt][nt][1]);
            pkq[mt][nt][1] = pk2(qacc[mt][nt][2], qacc[mt][nt][3]);
        }
    // ---- repack q into 32x32x16 B-operand layout (one-time) ----
    H8 bqf[4];
    {
        const int ntSel = (lane >> 4) & 1;           // = bit4 of s5
        const int srcBase = (lane & 15) + (lane & 32);
        #pragma unroll
        for (int kc = 0; kc < 4; ++kc)
            #pragma unroll
            for (int jp = 0; jp < 4; ++jp) {
                const int src = srcBase + ((jp >> 1) << 4);
                int v0 = __shfl((int)pkq[kc][0][jp & 1], src, 64);
                int v1 = __shfl((int)pkq[kc][1][jp & 1], src, 64);
                bqf[kc].u[jp] = (unsigned int)(ntSel ? v1 : v0);
            }
    }
    __syncthreads();                             // all waves done reading Wq image

    // ---- Prologue B: overwrite LDS with mem f16 images (convert + transpose) ----
    for (int i = 0; i < 4; ++i) {
        int id = t + i*1024;
        int m = id >> 3, cw = id & 7;
        const float* g = memB + m*64 + cw*8;
        float4 a0 = *(const float4*)g;
        float4 a1 = *(const float4*)(g + 4);
        sm128[m*8 + (cw ^ (m & 7))] =
            make_uint4(pk2(a0.x,a0.y), pk2(a0.z,a0.w), pk2(a1.x,a1.y), pk2(a1.z,a1.w));
    }
    __syncthreads();
    for (int i = 0; i < 4; ++i) {
        int id = t + i*1024;
        int w = id & 63, cm = id >> 6;
        unsigned int uu[4];
        #pragma unroll
        for (int p = 0; p < 4; ++p) {
            int m0 = cm*8 + 2*p, m1 = m0 + 1;
            unsigned short lo = smemu[m0*64 + (((w>>3) ^ (m0&7))<<3) + (w&7)];
            unsigned short hi = smemu[m1*64 + (((w>>3) ^ (m1&7))<<3) + (w&7)];
            uu[p] = (unsigned int)lo | ((unsigned int)hi << 16);
        }
        sm128[MEMT16 + w*64 + (cm ^ (w & 7))] = make_uint4(uu[0],uu[1],uu[2],uu[3]);
    }
    __syncthreads();

    // ========== single-pass flash loop: rotated + staggered per sq ==========
    // Online softmax is tile-order-invariant: each sq-group starts at mtile
    // sq*4 and wraps. Co-resident waves on a SIMD (same wv&3, sq=0..3) are
    // additionally offset by a one-time s_sleep so their phases interleave.
    if (sq == 1) __builtin_amdgcn_s_sleep(2);
    else if (sq == 2) __builtin_amdgcn_s_sleep(4);
    else if (sq == 3) __builtin_amdgcn_s_sleep(6);

    f32x16 Oa0 = (f32x16)0.f, Oa1 = (f32x16)0.f;
    float Ml = -1e30f, llp = 0.f;
    const int mt0 = sq * 4;

    H8 afc[4];
    #pragma unroll
    for (int kc = 0; kc < 4; ++kc)
        afc[kc].u4 = sm128[(mt0*32 + l31)*8 + (((kc<<1) + hh) ^ mswz)];

    for (int i = 0; i < 16; ++i) {
        const int mtile = (i + mt0) & 15;
        f32x16 Sa = (f32x16)0.f;
        __builtin_amdgcn_s_setprio(1);
        #pragma unroll
        for (int kc = 0; kc < 4; ++kc)
            Sa = __builtin_amdgcn_mfma_f32_32x32x16_f16(afc[kc].h8, bqf[kc].h8, Sa, 0, 0, 0);
        __builtin_amdgcn_s_setprio(0);
        if (i < 15) {
            const int mrow = ((i + 1 + mt0) & 15)*32 + l31;
            #pragma unroll
            for (int kc = 0; kc < 4; ++kc)
                afc[kc].u4 = sm128[mrow*8 + (((kc<<1) + hh) ^ mswz)];
        }
        const int c0 = mtile*4 + hh;
        H8 afP0, afP1, afP2, afP3;
        afP0.u4 = sm128[MEMT16 + l31*64        + ( c0      ^ mswz)];
        afP1.u4 = sm128[MEMT16 + l31*64        + ((c0 + 2) ^ mswz)];
        afP2.u4 = sm128[MEMT16 + (32 + l31)*64 + ( c0      ^ mswz)];
        afP3.u4 = sm128[MEMT16 + (32 + l31)*64 + ((c0 + 2) ^ mswz)];
        float m0 = fmaxf(fmaxf(Sa[0], Sa[1]), Sa[2]);
        float m1 = fmaxf(fmaxf(Sa[3], Sa[4]), Sa[5]);
        float m2 = fmaxf(fmaxf(Sa[6], Sa[7]), Sa[8]);
        float m3 = fmaxf(fmaxf(Sa[9], Sa[10]), Sa[11]);
        float m4 = fmaxf(fmaxf(Sa[12], Sa[13]), Sa[14]);
        float m5 = fmaxf(fmaxf(m0, m1), Sa[15]);
        float m6 = fmaxf(fmaxf(m2, m3), m4);
        float tmx = xhalf_max(fmaxf(m5, m6));
        // defer-max (T13): rescale only when running max grows by > 8 (log2).
        if (__any(tmx > Ml + 8.0f)) {
            float Mn = fmaxf(Ml, tmx);
            float al = __builtin_amdgcn_exp2f(Ml - Mn);
            Ml = Mn;
            llp *= al;
            #pragma unroll
            for (int g = 0; g < 16; ++g) { Oa0[g] *= al; Oa1[g] *= al; }
        }
        float pv[16];
        #pragma unroll
        for (int g = 0; g < 16; ++g) pv[g] = __builtin_amdgcn_exp2f(Sa[g] - Ml);
        float ts = (((pv[0]+pv[1])+(pv[2]+pv[3])) + ((pv[4]+pv[5])+(pv[6]+pv[7])))
                 + (((pv[8]+pv[9])+(pv[10]+pv[11])) + ((pv[12]+pv[13])+(pv[14]+pv[15])));
        llp += ts;
        uint2v rA0 = __builtin_amdgcn_permlane32_swap(pk2(pv[0],pv[1]),   pk2(pv[4],pv[5]),   false, false);
        uint2v rB0 = __builtin_amdgcn_permlane32_swap(pk2(pv[2],pv[3]),   pk2(pv[6],pv[7]),   false, false);
        uint2v rA1 = __builtin_amdgcn_permlane32_swap(pk2(pv[8],pv[9]),   pk2(pv[12],pv[13]), false, false);
        uint2v rB1 = __builtin_amdgcn_permlane32_swap(pk2(pv[10],pv[11]), pk2(pv[14],pv[15]), false, false);
        H8 bp0; bp0.u[0]=rA0[0]; bp0.u[1]=rB0[0]; bp0.u[2]=rA0[1]; bp0.u[3]=rB0[1];
        H8 bp1; bp1.u[0]=rA1[0]; bp1.u[1]=rB1[0]; bp1.u[2]=rA1[1]; bp1.u[3]=rB1[1];
        __builtin_amdgcn_s_setprio(1);
        Oa0 = __builtin_amdgcn_mfma_f32_32x32x16_f16(afP0.h8, bp0.h8, Oa0, 0, 0, 0);
        Oa0 = __builtin_amdgcn_mfma_f32_32x32x16_f16(afP1.h8, bp1.h8, Oa0, 0, 0, 0);
        Oa1 = __builtin_amdgcn_mfma_f32_32x32x16_f16(afP2.h8, bp0.h8, Oa1, 0, 0, 0);
        Oa1 = __builtin_amdgcn_mfma_f32_32x32x16_f16(afP3.h8, bp1.h8, Oa1, 0, 0, 0);
        __builtin_amdgcn_s_setprio(0);
    }

    // combine the two half-partials of the denominator (lane <-> lane^32)
    float inv = 1.0f / xhalf_sum(llp);

    // ---- store read_words ----
    {
        const int s = s0 + l31;
        float* op = out + ((size_t)(b*SSEQ + s)*4 + r)*WW;
        #pragma unroll
        for (int rq = 0; rq < 4; ++rq) {
            float4 o0 = make_float4(Oa0[rq*4+0]*inv, Oa0[rq*4+1]*inv,
                                    Oa0[rq*4+2]*inv, Oa0[rq*4+3]*inv);
            *(float4*)&op[rq*8 + hh*4] = o0;
            float4 o1 = make_float4(Oa1[rq*4+0]*inv, Oa1[rq*4+1]*inv,
                                    Oa1[rq*4+2]*inv, Oa1[rq*4+3]*inv);
            *(float4*)&op[32 + rq*8 + hh*4] = o1;
        }
    }

    // ---- final_state (b == 255): recompute scores, store normalized wts ----
    if (b == BB - 1) {
        const int s = s0 + l31;
        size_t base = (size_t)OUT1 + ((size_t)(s*4 + r) << 9);
        for (int mtile = 0; mtile < 16; ++mtile) {
            f32x16 Sa = (f32x16)0.f;
            const int mrow = mtile*32 + l31;
            #pragma unroll
            for (int kc = 0; kc < 4; ++kc) {
                H8 af; af.u4 = sm128[mrow*8 + (((kc<<1) + hh) ^ mswz)];
                Sa = __builtin_amdgcn_mfma_f32_32x32x16_f16(af.h8, bqf[kc].h8, Sa, 0, 0, 0);
            }
            #pragma unroll
            for (int rq = 0; rq < 4; ++rq) {
                float4 w4 = make_float4(
                    __builtin_amdgcn_exp2f(Sa[rq*4+0] - Ml) * inv,
                    __builtin_amdgcn_exp2f(Sa[rq*4+1] - Ml) * inv,
                    __builtin_amdgcn_exp2f(Sa[rq*4+2] - Ml) * inv,
                    __builtin_amdgcn_exp2f(Sa[rq*4+3] - Ml) * inv);
                *(float4*)&out[base + mtile*32 + rq*8 + hh*4] = w4;
            }
        }
    }
}

extern "C" void kernel_launch(void* const* d_in, const int* in_sizes, int n_in,
                              void* d_out, int out_size, void* d_ws, size_t ws_size,
                              hipStream_t stream) {
    const float* x    = (const float*)d_in[0];
    const int*   uid  = (const int*)  d_in[1];
    const float* uet  = (const float*)d_in[2];
    const float* Wp   = (const float*)d_in[3];
    const float* bp   = (const float*)d_in[4];
    const float* Wq   = (const float*)d_in[5];
    const float* mem  = (const float*)d_in[6];
    float* out = (float*)d_out;

    (void)hipFuncSetAttribute((const void*)attn_kernel,
                              hipFuncAttributeMaxDynamicSharedMemorySize, LDS_BYTES);
    attn_kernel<<<BB, 1024, LDS_BYTES, stream>>>(x, uid, uet, Wp, bp, Wq, mem, out);
}